// Round 6
// baseline (428.607 us; speedup 1.0000x reference)
//
#include <hip/hip_runtime.h>

// ---- problem constants ----
constexpr int B_  = 128;
constexpr int T_  = 24;
constexpr int E_  = 512;
constexpr int H_  = 512;
constexpr int V_  = 10000;
constexpr int G4  = 2048;   // 4*H
constexpr int TP1 = 25;     // T+1

typedef __attribute__((ext_vector_type(8))) short bf16x8;   // 8 bf16 = 4 VGPR
typedef __attribute__((ext_vector_type(4))) short short4v;  // 4 bf16 = 8 B
typedef __attribute__((ext_vector_type(4))) float f32x4;

#define MFMA_16x16x32_BF16(a, b, c) __builtin_amdgcn_mfma_f32_16x16x32_bf16((a), (b), (c), 0, 0, 0)

// fp32 -> bf16 round-to-nearest-even (bit-level, no header ABI dependence)
__device__ inline unsigned short f2bf(float f) {
    unsigned int u = __float_as_uint(f);
    unsigned int r = (u + 0x7FFFu + ((u >> 16) & 1u)) >> 16;
    return (unsigned short)r;
}

// async global->LDS, 16B per lane. LDS dest must be linear-in-lane.
__device__ inline void gl16(const unsigned short* g, unsigned short* l) {
    __builtin_amdgcn_global_load_lds(
        (const __attribute__((address_space(1))) unsigned int*)g,
        (__attribute__((address_space(3))) unsigned int*)l, 16, 0, 0);
}

// Bank swizzle used by the GEMM kernels' LDS tiles (see R5 notes).
__device__ inline int swz16(int row, int lq) {      // returns short offset
    return (((row << 2) | lq) ^ (row & 7)) << 3;
}

// ---------------------------------------------------------------------------
// All fp32 -> bf16 staging in ONE launch + barrier-state reset (graph-replay
// safe: runs first on the stream every launch).
// ---------------------------------------------------------------------------
__global__ __launch_bounds__(256) void k_cvt_all(const float* __restrict__ Wih,
                                                 const float* __restrict__ Whh,
                                                 const float* __restrict__ Wout,
                                                 const float* __restrict__ images,
                                                 unsigned short* __restrict__ dWih,
                                                 unsigned short* __restrict__ dWhh,
                                                 unsigned short* __restrict__ dWout,
                                                 unsigned short* __restrict__ dimg,
                                                 unsigned* __restrict__ bar) {
    int b = blockIdx.x;
    if (b == 0 && threadIdx.x == 0) { bar[0] = 0u; bar[1] = 0u; }
    const float* src; unsigned short* dst; int i;
    if (b < 1024)      { src = Wih;    dst = dWih;  i = b * 256 + threadIdx.x; }
    else if (b < 2048) { src = Whh;    dst = dWhh;  i = (b - 1024) * 256 + threadIdx.x; }
    else if (b < 7048) { src = Wout;   dst = dWout; i = (b - 2048) * 256 + threadIdx.x; }
    else               { src = images; dst = dimg;  i = (b - 7048) * 256 + threadIdx.x; }
    float4 v = ((const float4*)src)[i];
    short4v o;
    o[0] = (short)f2bf(v.x); o[1] = (short)f2bf(v.y);
    o[2] = (short)f2bf(v.z); o[3] = (short)f2bf(v.w);
    ((short4v*)dst)[i] = o;
}

// ---------------------------------------------------------------------------
// Embedding gather -> bf16, padding_idx(0) -> zeros.
// ---------------------------------------------------------------------------
__global__ __launch_bounds__(256) void k_embed(const float* __restrict__ Wemb,
                                               const int* __restrict__ captions,
                                               unsigned short* __restrict__ Xemb) {
    int i = blockIdx.x * 256 + threadIdx.x;     // one thread per 4 elems
    if (i >= 3072 * 128) return;
    int row = i >> 7;                           // m = t*128 + b
    int k4  = i & 127;
    int b = row & 127, t = row >> 7;
    int tok = captions[b * T_ + t];
    short4v o = {0, 0, 0, 0};
    if (tok > 0 && tok < V_) {                  // tok==0 is padding -> zeros
        float4 v = ((const float4*)(Wemb + (long)tok * E_))[k4];
        o[0] = (short)f2bf(v.x); o[1] = (short)f2bf(v.y);
        o[2] = (short)f2bf(v.z); o[3] = (short)f2bf(v.w);
    }
    ((short4v*)Xemb)[(long)row * 128 + k4] = o;
}

// ---------------------------------------------------------------------------
// t=0 one-hot row (only) + (captions_length - 1) tail.
// ---------------------------------------------------------------------------
__global__ __launch_bounds__(256) void k_start(float* __restrict__ out,
                                               const int* __restrict__ cap_len) {
    int idx = blockIdx.x * 256 + threadIdx.x;
    constexpr int Q = V_ / 4;                    // 2500 float4 per row
    if (idx < B_ * Q) {
        int b = idx / Q;
        int q = idx - b * Q;
        float4 zero = {0.f, 0.f, 0.f, 0.f};
        float4 one1 = {0.f, 1.f, 0.f, 0.f};      // one-hot at v=1
        ((float4*)out)[(long)b * (TP1 * Q) + q] = (q == 0) ? one1 : zero;
    }
    if (idx < B_) {
        out[(size_t)B_ * TP1 * V_ + idx] = (float)(cap_len[idx] - 1);
    }
}

// ---------------------------------------------------------------------------
// P[m][n] = Xemb[m].Wih[n] + bih[n] + bhh[n]  (fp32). M=3072, N=2048, K=512.
// 128x128 LDS-staged tiles, XCD-swizzled. (Unchanged from R5 — passing.)
// ---------------------------------------------------------------------------
__global__ __launch_bounds__(256) void k_pregemm(const unsigned short* __restrict__ Xemb,
                                                 const unsigned short* __restrict__ Wih,
                                                 const float* __restrict__ bih,
                                                 const float* __restrict__ bhh,
                                                 float* __restrict__ P) {
    __shared__ unsigned short ldsA[2][4096];     // [buf][128*32] swizzled
    __shared__ unsigned short ldsB[2][4096];
    int bid = blockIdx.x;
    int xcd = bid & 7;
    int q   = bid >> 3;                          // 0..47
    int MI  = xcd * 3 + (q % 3);                 // 0..23
    int NI  = q / 3;                             // 0..15
    int i    = threadIdx.x;
    int w = i >> 6, lane = i & 63;
    int lm = lane & 15, lq = lane >> 4;
    int wr = w >> 1, wc = w & 1;

    int mm0 = ((i >> 2) & 7) ^ ((i >> 4) & 1);   // writer inverse swizzle
    int li  = i ^ mm0;
    const unsigned short* gA = Xemb + (size_t)(MI * 128 + (li >> 2)) * 512 + (li & 3) * 8;
    const unsigned short* gB = Wih  + (size_t)(NI * 128 + (li >> 2)) * 512 + (li & 3) * 8;
    unsigned short* lA = &ldsA[0][0] + i * 8;
    unsigned short* lB = &ldsB[0][0] + i * 8;

    auto stage = [&](int buf, int ks) {
        int go = ks * 32;
        gl16(gA + go,            lA + buf * 4096);
        gl16(gA + go + 64 * 512, lA + buf * 4096 + 2048);
        gl16(gB + go,            lB + buf * 4096);
        gl16(gB + go + 64 * 512, lB + buf * 4096 + 2048);
    };

    f32x4 acc[4][4] = {};
    stage(0, 0);
    for (int ksi = 0; ksi < 16; ksi++) {
        int cur = ksi & 1;
        if (ksi < 15) stage(cur ^ 1, ksi + 1);
        __syncthreads();
        bf16x8 af[4], bfr[4];
        #pragma unroll
        for (int mi = 0; mi < 4; mi++)
            af[mi] = *(const bf16x8*)&ldsA[cur][swz16(wr * 64 + mi * 16 + lm, lq)];
        #pragma unroll
        for (int ni = 0; ni < 4; ni++)
            bfr[ni] = *(const bf16x8*)&ldsB[cur][swz16(wc * 64 + ni * 16 + lm, lq)];
        #pragma unroll
        for (int mi = 0; mi < 4; mi++)
            #pragma unroll
            for (int ni = 0; ni < 4; ni++)
                acc[mi][ni] = MFMA_16x16x32_BF16(af[mi], bfr[ni], acc[mi][ni]);
        __syncthreads();
    }

    float bias[4];
    #pragma unroll
    for (int ni = 0; ni < 4; ni++) {
        int n = NI * 128 + wc * 64 + ni * 16 + lm;
        bias[ni] = bih[n] + bhh[n];
    }
    #pragma unroll
    for (int mi = 0; mi < 4; mi++) {
        #pragma unroll
        for (int r = 0; r < 4; r++) {
            int m = MI * 128 + wr * 64 + mi * 16 + lq * 4 + r;
            #pragma unroll
            for (int ni = 0; ni < 4; ni++) {
                int n = NI * 128 + wc * 64 + ni * 16 + lm;
                P[(size_t)m * G4 + n] = acc[mi][ni][r] + bias[ni];
            }
        }
    }
}

// ---------------------------------------------------------------------------
// Persistent LSTM recurrence, FENCE-FREE coherence.
// 256 blocks x 256 thr (co-resident by capacity; R2 proved completion with
// this geometry). Block = (MI 0..7, HG 0..31); wave w owns K-slice
// [w*128,+128) and the cell for row r==w. Whh bf16 frags live in registers
// for all 24 steps (64 VGPR); c lives in registers.
// Cross-block h exchange goes through AGENT-scope relaxed atomics (uint,
// coherence-point ops) -> NO __threadfence(), so the per-XCD L2 (holding
// Whh/P/c lines) is never invalidated. Each wave drains its own h stores
// with vmcnt(0) before the block arrives at the counter barrier.
// ---------------------------------------------------------------------------
__global__ __launch_bounds__(256, 1) void k_lstm(const float* __restrict__ P,
                                                 const unsigned short* __restrict__ h0,
                                                 unsigned* __restrict__ hx0,
                                                 unsigned* __restrict__ hx1,
                                                 unsigned short* __restrict__ Hall,
                                                 const unsigned short* __restrict__ Whh,
                                                 unsigned* __restrict__ bar) {
    __shared__ float part[16][4][64];            // [g*4+r][wave][lane]
    int w    = threadIdx.x >> 6;                 // 0..3 (K-slice / cell row)
    int lane = threadIdx.x & 63;
    int lm = lane & 15, lq = lane >> 4;
    int MI = blockIdx.x >> 5;                    // 0..7
    int HG = blockIdx.x & 31;                    // 0..31
    int hcol = HG * 16 + lm;
    int ks = w * 128;
    int brow = MI * 16 + lq * 4 + w;             // this lane's cell row (b)

    // resident Whh fragments (bf16), reused all 24 steps
    bf16x8 bw[4][4];                             // [gate][kk]
    #pragma unroll
    for (int g = 0; g < 4; g++)
        #pragma unroll
        for (int kk = 0; kk < 4; kk++)
            bw[g][kk] = *(const bf16x8*)((const short*)Whh +
                          (size_t)(g * 512 + hcol) * 512 + ks + kk * 32 + lq * 8);

    float cp = 0.f;                              // c[brow][hcol] in-register

    for (int t = 0; t < T_; t++) {
        // ---- A fragments (h rows MI*16+lm, this wave's K-slice) ----
        bf16x8 a[4];
        if (t == 0) {
            const unsigned short* A = h0 + (size_t)(MI * 16 + lm) * 512 + ks;
            #pragma unroll
            for (int kk = 0; kk < 4; kk++)
                a[kk] = *(const bf16x8*)(A + kk * 32 + lq * 8);
        } else {
            const unsigned* HX = (t & 1) ? hx1 : hx0;   // written at step t-1
            const unsigned* A = HX + ((size_t)(MI * 16 + lm) * 512 + ks) / 2;
            #pragma unroll
            for (int kk = 0; kk < 4; kk++) {
                union { unsigned u[4]; bf16x8 v; } cv;
                #pragma unroll
                for (int j = 0; j < 4; j++)
                    cv.u[j] = __hip_atomic_load(A + kk * 16 + lq * 4 + j,
                                                __ATOMIC_RELAXED, __HIP_MEMORY_SCOPE_AGENT);
                a[kk] = cv.v;
            }
        }

        // ---- P (xW + bias) for this wave's cell row ----
        const float* Pr = P + (size_t)t * B_ * G4 + (size_t)brow * G4;
        float pv0 = Pr[0 * 512 + hcol];
        float pv1 = Pr[1 * 512 + hcol];
        float pv2 = Pr[2 * 512 + hcol];
        float pv3 = Pr[3 * 512 + hcol];

        // ---- GEMM slice ----
        f32x4 acc[4] = {};
        #pragma unroll
        for (int kk = 0; kk < 4; kk++) {
            acc[0] = MFMA_16x16x32_BF16(a[kk], bw[0][kk], acc[0]);
            acc[1] = MFMA_16x16x32_BF16(a[kk], bw[1][kk], acc[1]);
            acc[2] = MFMA_16x16x32_BF16(a[kk], bw[2][kk], acc[2]);
            acc[3] = MFMA_16x16x32_BF16(a[kk], bw[3][kk], acc[3]);
        }

        #pragma unroll
        for (int g = 0; g < 4; g++)
            #pragma unroll
            for (int r = 0; r < 4; r++)
                part[g * 4 + r][w][lane] = acc[g][r];
        __syncthreads();

        // ---- reduce + cell (wave w handles row r==w) ----
        float gi = part[0*4+w][0][lane] + part[0*4+w][1][lane] + part[0*4+w][2][lane] + part[0*4+w][3][lane] + pv0;
        float gf = part[1*4+w][0][lane] + part[1*4+w][1][lane] + part[1*4+w][2][lane] + part[1*4+w][3][lane] + pv1;
        float gg = part[2*4+w][0][lane] + part[2*4+w][1][lane] + part[2*4+w][2][lane] + part[2*4+w][3][lane] + pv2;
        float go = part[3*4+w][0][lane] + part[3*4+w][1][lane] + part[3*4+w][2][lane] + part[3*4+w][3][lane] + pv3;
        float si = 1.f / (1.f + expf(-gi));
        float sf = 1.f / (1.f + expf(-gf));
        float so = 1.f / (1.f + expf(-go));
        float cn = sf * cp + si * tanhf(gg);
        float hn = so * tanhf(cn);
        cp = cn;
        unsigned short hb = f2bf(hn);
        Hall[(size_t)t * (B_ * H_) + brow * 512 + hcol] = hb;   // normal store

        if (t < T_ - 1) {
            // pair adjacent hcols into one uint, agent-scope store (coherent)
            unsigned up = ((unsigned)(unsigned short)__shfl_down((int)hb, 1) << 16) | (unsigned)hb;
            unsigned* HW = (t & 1) ? hx0 : hx1;  // step t writes; step t+1 reads
            if (!(lm & 1))
                __hip_atomic_store(HW + (brow * 512 + hcol) / 2, up,
                                   __ATOMIC_RELAXED, __HIP_MEMORY_SCOPE_AGENT);
            // each wave drains ITS OWN h stores before the block arrives
            asm volatile("s_waitcnt vmcnt(0)" ::: "memory");
            __syncthreads();
            if (threadIdx.x == 0) {
                unsigned prev = __hip_atomic_fetch_add(&bar[0], 1u, __ATOMIC_RELAXED,
                                                       __HIP_MEMORY_SCOPE_AGENT);
                if (prev == (unsigned)(t * 256 + 255)) {       // last arriver
                    __hip_atomic_store(&bar[1], (unsigned)(t + 1), __ATOMIC_RELAXED,
                                       __HIP_MEMORY_SCOPE_AGENT);
                } else {
                    while (__hip_atomic_load(&bar[1], __ATOMIC_RELAXED,
                                             __HIP_MEMORY_SCOPE_AGENT) < (unsigned)(t + 1))
                        __builtin_amdgcn_s_sleep(8);
                }
            }
            __syncthreads();
        }
    }
}

// ---------------------------------------------------------------------------
// Logits: Hall[3072,512](bf16) @ Wout_bf^T + b_out -> fp32 out[b][t+1][v].
// (Unchanged from R5 — passing at 77 us.)
// ---------------------------------------------------------------------------
__global__ __launch_bounds__(256) void k_logits(const unsigned short* __restrict__ Hall,
                                                const unsigned short* __restrict__ Wout,
                                                const float* __restrict__ bout,
                                                float* __restrict__ out) {
    __shared__ unsigned short ldsA[2][4096];     // [buf][128*32] swizzled
    __shared__ unsigned short ldsB[2][4096];
    int bid = blockIdx.x;
    int xcd = bid & 7;
    int q   = bid >> 3;                          // 0..236
    int MI  = xcd * 3 + (q % 3);                 // 0..23 (== timestep t)
    int NI  = q / 3;                             // 0..78
    int i    = threadIdx.x;
    int w = i >> 6, lane = i & 63;
    int lm = lane & 15, lq = lane >> 4;
    int wr = w >> 1, wc = w & 1;

    int mm0 = ((i >> 2) & 7) ^ ((i >> 4) & 1);   // writer inverse swizzle
    int li  = i ^ mm0;
    const unsigned short* gA = Hall + (size_t)(MI * 128 + (li >> 2)) * 512 + (li & 3) * 8;
    const unsigned short* gB = Wout + (size_t)(NI * 128 + (li >> 2)) * 512 + (li & 3) * 8;
    unsigned short* lA = &ldsA[0][0] + i * 8;
    unsigned short* lB = &ldsB[0][0] + i * 8;

    auto stage = [&](int buf, int ks) {
        int go = ks * 32;
        gl16(gA + go,            lA + buf * 4096);
        gl16(gA + go + 64 * 512, lA + buf * 4096 + 2048);
        gl16(gB + go,            lB + buf * 4096);
        gl16(gB + go + 64 * 512, lB + buf * 4096 + 2048);
    };

    f32x4 acc[4][4] = {};
    stage(0, 0);
    for (int ksi = 0; ksi < 16; ksi++) {
        int cur = ksi & 1;
        if (ksi < 15) stage(cur ^ 1, ksi + 1);
        __syncthreads();                         // staging of cur complete
        bf16x8 af[4], bfr[4];
        #pragma unroll
        for (int mi = 0; mi < 4; mi++)
            af[mi] = *(const bf16x8*)&ldsA[cur][swz16(wr * 64 + mi * 16 + lm, lq)];
        #pragma unroll
        for (int ni = 0; ni < 4; ni++)
            bfr[ni] = *(const bf16x8*)&ldsB[cur][swz16(wc * 64 + ni * 16 + lm, lq)];
        #pragma unroll
        for (int mi = 0; mi < 4; mi++)
            #pragma unroll
            for (int ni = 0; ni < 4; ni++)
                acc[mi][ni] = MFMA_16x16x32_BF16(af[mi], bfr[ni], acc[mi][ni]);
        __syncthreads();                         // done reading cur
    }

    #pragma unroll
    for (int mi = 0; mi < 4; mi++) {
        #pragma unroll
        for (int r = 0; r < 4; r++) {
            int b = wr * 64 + mi * 16 + lq * 4 + r;
            float* orow = out + ((size_t)b * TP1 + MI + 1) * V_;
            #pragma unroll
            for (int ni = 0; ni < 4; ni++) {
                int n = NI * 128 + wc * 64 + ni * 16 + lm;
                if (n < V_) orow[n] = acc[mi][ni][r] + bout[n];
            }
        }
    }
}

// ---------------------------------------------------------------------------
extern "C" void kernel_launch(void* const* d_in, const int* in_sizes, int n_in,
                              void* d_out, int out_size, void* d_ws, size_t ws_size,
                              hipStream_t stream) {
    const float* images   = (const float*)d_in[0];
    const int*   captions = (const int*)d_in[1];
    const int*   cap_len  = (const int*)d_in[2];
    const float* Wemb     = (const float*)d_in[3];
    const float* Wih      = (const float*)d_in[4];
    const float* Whh      = (const float*)d_in[5];
    const float* bih      = (const float*)d_in[6];
    const float* bhh      = (const float*)d_in[7];
    const float* Wout     = (const float*)d_in[8];
    const float* bout     = (const float*)d_in[9];
    float* out = (float*)d_out;

    // workspace layout (all sizes multiples of 256B)
    char* ws = (char*)d_ws;
    unsigned short* Wih_bf  = (unsigned short*)(ws);              //  2,097,152
    unsigned short* Whh_bf  = (unsigned short*)(ws + 2097152);    //  2,097,152
    unsigned short* Wout_bf = (unsigned short*)(ws + 4194304);    // 10,354,688
    unsigned short* Xemb    = (unsigned short*)(ws + 14548992);   //  3,145,728
    unsigned short* Hall    = (unsigned short*)(ws + 17694720);   //  3,145,728
    unsigned short* h0      = (unsigned short*)(ws + 20840448);   //    131,072
    unsigned*       hx0     = (unsigned*)(ws + 20971520);         //    131,072
    unsigned*       hx1     = (unsigned*)(ws + 21102592);         //    131,072
    unsigned*       bar     = (unsigned*)(ws + 21233664);         //        256
    constexpr size_t P_OFF   = 21233920;
    constexpr size_t WS_NEED = P_OFF + 25165824;   // 46,399,744
    float* P = (ws_size >= WS_NEED) ? (float*)(ws + P_OFF) : (float*)d_out;

    // staging: all fp32->bf16 in one launch (+ barrier reset) + embedding
    k_cvt_all<<<7112, 256, 0, stream>>>(Wih, Whh, Wout, images,
                                        Wih_bf, Whh_bf, Wout_bf, h0, bar);
    k_embed<<<1536, 256, 0, stream>>>(Wemb, captions, Xemb);

    // hoisted input GEMM: P = Xemb @ Wih^T + (bih + bhh)
    k_pregemm<<<384, 256, 0, stream>>>(Xemb, Wih_bf, bih, bhh, P);

    // whole recurrence in ONE persistent kernel (fence-free barrier)
    k_lstm<<<256, 256, 0, stream>>>(P, h0, hx0, hx1, Hall, Whh_bf, bar);

    // t=0 one-hot row + length tail
    k_start<<<1250, 256, 0, stream>>>(out, cap_len);

    // logits, LDS-staged 128x128 tiles
    k_logits<<<1896, 256, 0, stream>>>(Hall, Wout_bf, bout, out);
}

// Round 7
// 340.681 us; speedup vs baseline: 1.2581x; 1.2581x over previous
//
#include <hip/hip_runtime.h>

// ---- problem constants ----
constexpr int B_  = 128;
constexpr int T_  = 24;
constexpr int E_  = 512;
constexpr int H_  = 512;
constexpr int V_  = 10000;
constexpr int G4  = 2048;   // 4*H
constexpr int TP1 = 25;     // T+1

typedef __attribute__((ext_vector_type(8))) short bf16x8;   // 8 bf16 = 4 VGPR
typedef __attribute__((ext_vector_type(4))) short short4v;  // 4 bf16 = 8 B
typedef __attribute__((ext_vector_type(4))) float f32x4;

#define MFMA_16x16x32_BF16(a, b, c) __builtin_amdgcn_mfma_f32_16x16x32_bf16((a), (b), (c), 0, 0, 0)

// fp32 -> bf16 round-to-nearest-even (bit-level, no header ABI dependence)
__device__ inline unsigned short f2bf(float f) {
    unsigned int u = __float_as_uint(f);
    unsigned int r = (u + 0x7FFFu + ((u >> 16) & 1u)) >> 16;
    return (unsigned short)r;
}

// async global->LDS, 16B per lane. LDS dest must be linear-in-lane.
__device__ inline void gl16(const unsigned short* g, unsigned short* l) {
    __builtin_amdgcn_global_load_lds(
        (const __attribute__((address_space(1))) unsigned int*)g,
        (__attribute__((address_space(3))) unsigned int*)l, 16, 0, 0);
}

// Bank swizzle used by the GEMM kernels' LDS tiles.
__device__ inline int swz16(int row, int lq) {      // returns short offset
    return (((row << 2) | lq) ^ (row & 7)) << 3;
}

// ---------------------------------------------------------------------------
// All fp32 -> bf16 staging in ONE launch + flag-state reset (graph-replay
// safe: runs first on the stream every launch). 32 counters, 128B apart.
// ---------------------------------------------------------------------------
__global__ __launch_bounds__(256) void k_cvt_all(const float* __restrict__ Wih,
                                                 const float* __restrict__ Whh,
                                                 const float* __restrict__ Wout,
                                                 const float* __restrict__ images,
                                                 unsigned short* __restrict__ dWih,
                                                 unsigned short* __restrict__ dWhh,
                                                 unsigned short* __restrict__ dWout,
                                                 unsigned short* __restrict__ dimg,
                                                 unsigned* __restrict__ cnt) {
    int b = blockIdx.x;
    if (b == 0 && threadIdx.x < 32) cnt[threadIdx.x * 32] = 0u;
    const float* src; unsigned short* dst; int i;
    if (b < 1024)      { src = Wih;    dst = dWih;  i = b * 256 + threadIdx.x; }
    else if (b < 2048) { src = Whh;    dst = dWhh;  i = (b - 1024) * 256 + threadIdx.x; }
    else if (b < 7048) { src = Wout;   dst = dWout; i = (b - 2048) * 256 + threadIdx.x; }
    else               { src = images; dst = dimg;  i = (b - 7048) * 256 + threadIdx.x; }
    float4 v = ((const float4*)src)[i];
    short4v o;
    o[0] = (short)f2bf(v.x); o[1] = (short)f2bf(v.y);
    o[2] = (short)f2bf(v.z); o[3] = (short)f2bf(v.w);
    ((short4v*)dst)[i] = o;
}

// ---------------------------------------------------------------------------
// Embedding gather -> bf16, padding_idx(0) -> zeros.
// ---------------------------------------------------------------------------
__global__ __launch_bounds__(256) void k_embed(const float* __restrict__ Wemb,
                                               const int* __restrict__ captions,
                                               unsigned short* __restrict__ Xemb) {
    int i = blockIdx.x * 256 + threadIdx.x;     // one thread per 4 elems
    if (i >= 3072 * 128) return;
    int row = i >> 7;                           // m = t*128 + b
    int k4  = i & 127;
    int b = row & 127, t = row >> 7;
    int tok = captions[b * T_ + t];
    short4v o = {0, 0, 0, 0};
    if (tok > 0 && tok < V_) {                  // tok==0 is padding -> zeros
        float4 v = ((const float4*)(Wemb + (long)tok * E_))[k4];
        o[0] = (short)f2bf(v.x); o[1] = (short)f2bf(v.y);
        o[2] = (short)f2bf(v.z); o[3] = (short)f2bf(v.w);
    }
    ((short4v*)Xemb)[(long)row * 128 + k4] = o;
}

// ---------------------------------------------------------------------------
// t=0 one-hot row (only) + (captions_length - 1) tail.
// ---------------------------------------------------------------------------
__global__ __launch_bounds__(256) void k_start(float* __restrict__ out,
                                               const int* __restrict__ cap_len) {
    int idx = blockIdx.x * 256 + threadIdx.x;
    constexpr int Q = V_ / 4;                    // 2500 float4 per row
    if (idx < B_ * Q) {
        int b = idx / Q;
        int q = idx - b * Q;
        float4 zero = {0.f, 0.f, 0.f, 0.f};
        float4 one1 = {0.f, 1.f, 0.f, 0.f};      // one-hot at v=1
        ((float4*)out)[(long)b * (TP1 * Q) + q] = (q == 0) ? one1 : zero;
    }
    if (idx < B_) {
        out[(size_t)B_ * TP1 * V_ + idx] = (float)(cap_len[idx] - 1);
    }
}

// ---------------------------------------------------------------------------
// P[m][n] = Xemb[m].Wih[n] + bih[n] + bhh[n]  (fp32). M=3072, N=2048, K=512.
// 128x128 LDS-staged tiles, XCD-swizzled. (Unchanged — passing.)
// ---------------------------------------------------------------------------
__global__ __launch_bounds__(256) void k_pregemm(const unsigned short* __restrict__ Xemb,
                                                 const unsigned short* __restrict__ Wih,
                                                 const float* __restrict__ bih,
                                                 const float* __restrict__ bhh,
                                                 float* __restrict__ P) {
    __shared__ unsigned short ldsA[2][4096];     // [buf][128*32] swizzled
    __shared__ unsigned short ldsB[2][4096];
    int bid = blockIdx.x;
    int xcd = bid & 7;
    int q   = bid >> 3;                          // 0..47
    int MI  = xcd * 3 + (q % 3);                 // 0..23
    int NI  = q / 3;                             // 0..15
    int i    = threadIdx.x;
    int w = i >> 6, lane = i & 63;
    int lm = lane & 15, lq = lane >> 4;
    int wr = w >> 1, wc = w & 1;

    int mm0 = ((i >> 2) & 7) ^ ((i >> 4) & 1);   // writer inverse swizzle
    int li  = i ^ mm0;
    const unsigned short* gA = Xemb + (size_t)(MI * 128 + (li >> 2)) * 512 + (li & 3) * 8;
    const unsigned short* gB = Wih  + (size_t)(NI * 128 + (li >> 2)) * 512 + (li & 3) * 8;
    unsigned short* lA = &ldsA[0][0] + i * 8;
    unsigned short* lB = &ldsB[0][0] + i * 8;

    auto stage = [&](int buf, int ks) {
        int go = ks * 32;
        gl16(gA + go,            lA + buf * 4096);
        gl16(gA + go + 64 * 512, lA + buf * 4096 + 2048);
        gl16(gB + go,            lB + buf * 4096);
        gl16(gB + go + 64 * 512, lB + buf * 4096 + 2048);
    };

    f32x4 acc[4][4] = {};
    stage(0, 0);
    for (int ksi = 0; ksi < 16; ksi++) {
        int cur = ksi & 1;
        if (ksi < 15) stage(cur ^ 1, ksi + 1);
        __syncthreads();
        bf16x8 af[4], bfr[4];
        #pragma unroll
        for (int mi = 0; mi < 4; mi++)
            af[mi] = *(const bf16x8*)&ldsA[cur][swz16(wr * 64 + mi * 16 + lm, lq)];
        #pragma unroll
        for (int ni = 0; ni < 4; ni++)
            bfr[ni] = *(const bf16x8*)&ldsB[cur][swz16(wc * 64 + ni * 16 + lm, lq)];
        #pragma unroll
        for (int mi = 0; mi < 4; mi++)
            #pragma unroll
            for (int ni = 0; ni < 4; ni++)
                acc[mi][ni] = MFMA_16x16x32_BF16(af[mi], bfr[ni], acc[mi][ni]);
        __syncthreads();
    }

    float bias[4];
    #pragma unroll
    for (int ni = 0; ni < 4; ni++) {
        int n = NI * 128 + wc * 64 + ni * 16 + lm;
        bias[ni] = bih[n] + bhh[n];
    }
    #pragma unroll
    for (int mi = 0; mi < 4; mi++) {
        #pragma unroll
        for (int r = 0; r < 4; r++) {
            int m = MI * 128 + wr * 64 + mi * 16 + lq * 4 + r;
            #pragma unroll
            for (int ni = 0; ni < 4; ni++) {
                int n = NI * 128 + wc * 64 + ni * 16 + lm;
                P[(size_t)m * G4 + n] = acc[mi][ni][r] + bias[ni];
            }
        }
    }
}

// ---------------------------------------------------------------------------
// Persistent LSTM recurrence with PER-MI-GROUP octet flags (no global
// barrier). Batch rows don't interact: block (MI,HG) only ever exchanges h
// with the 31 other blocks of its MI group. Wave w consumes h cols
// [w*128,+128) = exactly octet w's 8 producer blocks (HG in [8w,8w+8)).
// Producer: after h stores drain (vmcnt 0) + __syncthreads, thread0 adds 1
// to cnt[MI*4 + (HG>>3)] (cumulative). Consumer wave w at step t polls
// cnt[MI*4+w] >= 8*t. Waiting on all 4 octets at step t also excludes the
// slot-overwrite hazard (a block stores h[t] only after all 32 same-MI
// blocks finished step t-1, whose reads of the t&1 slot precede their
// signals). All h traffic via agent-scope relaxed atomics (L2-bypass) ->
// no threadfence, per-XCD L2 (Whh frags, P) never invalidated.
// ---------------------------------------------------------------------------
__global__ __launch_bounds__(256, 1) void k_lstm(const float* __restrict__ P,
                                                 const unsigned short* __restrict__ h0,
                                                 unsigned* __restrict__ hx0,
                                                 unsigned* __restrict__ hx1,
                                                 unsigned short* __restrict__ Hall,
                                                 const unsigned short* __restrict__ Whh,
                                                 unsigned* __restrict__ cnt) {
    __shared__ float part[16][4][64];            // [g*4+r][wave][lane]
    int w    = threadIdx.x >> 6;                 // 0..3 (K-slice / cell row)
    int lane = threadIdx.x & 63;
    int lm = lane & 15, lq = lane >> 4;
    int MI = blockIdx.x >> 5;                    // 0..7
    int HG = blockIdx.x & 31;                    // 0..31
    int hcol = HG * 16 + lm;
    int ks = w * 128;
    int brow = MI * 16 + lq * 4 + w;             // this lane's cell row (b)
    unsigned* myCnt = cnt + (MI * 4 + (HG >> 3)) * 32;   // producer counter
    unsigned* rdCnt = cnt + (MI * 4 + w) * 32;           // consumer counter

    // resident Whh fragments (bf16), reused all 24 steps
    bf16x8 bw[4][4];                             // [gate][kk]
    #pragma unroll
    for (int g = 0; g < 4; g++)
        #pragma unroll
        for (int kk = 0; kk < 4; kk++)
            bw[g][kk] = *(const bf16x8*)((const short*)Whh +
                          (size_t)(g * 512 + hcol) * 512 + ks + kk * 32 + lq * 8);

    float cp = 0.f;                              // c[brow][hcol] in-register

    for (int t = 0; t < T_; t++) {
        // ---- P (xW + bias): issue before the poll so it flies during it ----
        const float* Pr = P + (size_t)t * B_ * G4 + (size_t)brow * G4;
        float pv0 = Pr[0 * 512 + hcol];
        float pv1 = Pr[1 * 512 + hcol];
        float pv2 = Pr[2 * 512 + hcol];
        float pv3 = Pr[3 * 512 + hcol];

        // ---- A fragments (h rows MI*16+lm, this wave's K-slice) ----
        bf16x8 a[4];
        if (t == 0) {
            const unsigned short* A = h0 + (size_t)(MI * 16 + lm) * 512 + ks;
            #pragma unroll
            for (int kk = 0; kk < 4; kk++)
                a[kk] = *(const bf16x8*)(A + kk * 32 + lq * 8);
        } else {
            // wave-level wait: octet-w producers all stored h[t-1]
            if (lane == 0) {
                unsigned want = (unsigned)(8 * t);
                while (__hip_atomic_load(rdCnt, __ATOMIC_RELAXED,
                                         __HIP_MEMORY_SCOPE_AGENT) < want)
                    __builtin_amdgcn_s_sleep(1);
            }
            __builtin_amdgcn_wave_barrier();
            asm volatile("" ::: "memory");
            const unsigned long long* A = (const unsigned long long*)
                (((t & 1) ? hx1 : hx0) + ((size_t)(MI * 16 + lm) * 512 + ks) / 2);
            #pragma unroll
            for (int kk = 0; kk < 4; kk++) {
                union { unsigned long long q[2]; bf16x8 v; } cv;
                cv.q[0] = __hip_atomic_load(A + kk * 8 + lq * 2,
                                            __ATOMIC_RELAXED, __HIP_MEMORY_SCOPE_AGENT);
                cv.q[1] = __hip_atomic_load(A + kk * 8 + lq * 2 + 1,
                                            __ATOMIC_RELAXED, __HIP_MEMORY_SCOPE_AGENT);
                a[kk] = cv.v;
            }
        }

        // ---- GEMM slice ----
        f32x4 acc[4] = {};
        #pragma unroll
        for (int kk = 0; kk < 4; kk++) {
            acc[0] = MFMA_16x16x32_BF16(a[kk], bw[0][kk], acc[0]);
            acc[1] = MFMA_16x16x32_BF16(a[kk], bw[1][kk], acc[1]);
            acc[2] = MFMA_16x16x32_BF16(a[kk], bw[2][kk], acc[2]);
            acc[3] = MFMA_16x16x32_BF16(a[kk], bw[3][kk], acc[3]);
        }

        #pragma unroll
        for (int g = 0; g < 4; g++)
            #pragma unroll
            for (int r = 0; r < 4; r++)
                part[g * 4 + r][w][lane] = acc[g][r];
        __syncthreads();

        // ---- reduce + cell (wave w handles row r==w) ----
        float gi = part[0*4+w][0][lane] + part[0*4+w][1][lane] + part[0*4+w][2][lane] + part[0*4+w][3][lane] + pv0;
        float gf = part[1*4+w][0][lane] + part[1*4+w][1][lane] + part[1*4+w][2][lane] + part[1*4+w][3][lane] + pv1;
        float gg = part[2*4+w][0][lane] + part[2*4+w][1][lane] + part[2*4+w][2][lane] + part[2*4+w][3][lane] + pv2;
        float go = part[3*4+w][0][lane] + part[3*4+w][1][lane] + part[3*4+w][2][lane] + part[3*4+w][3][lane] + pv3;
        float si = 1.f / (1.f + expf(-gi));
        float sf = 1.f / (1.f + expf(-gf));
        float so = 1.f / (1.f + expf(-go));
        float cn = sf * cp + si * tanhf(gg);
        float hn = so * tanhf(cn);
        cp = cn;
        unsigned short hb = f2bf(hn);
        Hall[(size_t)t * (B_ * H_) + brow * 512 + hcol] = hb;   // normal store

        if (t < T_ - 1) {
            // pair adjacent hcols into one uint, agent-scope store (coherent)
            unsigned up = ((unsigned)(unsigned short)__shfl_down((int)hb, 1) << 16) | (unsigned)hb;
            unsigned* HW = (t & 1) ? hx0 : hx1;  // step t writes; t+1 reads
            if (!(lm & 1))
                __hip_atomic_store(HW + (brow * 512 + hcol) / 2, up,
                                   __ATOMIC_RELAXED, __HIP_MEMORY_SCOPE_AGENT);
            // each wave drains ITS OWN h stores before the block signals
            asm volatile("s_waitcnt vmcnt(0)" ::: "memory");
            __syncthreads();
            if (threadIdx.x == 0)
                __hip_atomic_fetch_add(myCnt, 1u, __ATOMIC_RELAXED,
                                       __HIP_MEMORY_SCOPE_AGENT);
            __syncthreads();
        }
    }
}

// ---------------------------------------------------------------------------
// Logits: Hall[3072,512](bf16) @ Wout_bf^T + b_out -> fp32 out[b][t+1][v].
// (Unchanged — 77 us.)
// ---------------------------------------------------------------------------
__global__ __launch_bounds__(256) void k_logits(const unsigned short* __restrict__ Hall,
                                                const unsigned short* __restrict__ Wout,
                                                const float* __restrict__ bout,
                                                float* __restrict__ out) {
    __shared__ unsigned short ldsA[2][4096];     // [buf][128*32] swizzled
    __shared__ unsigned short ldsB[2][4096];
    int bid = blockIdx.x;
    int xcd = bid & 7;
    int q   = bid >> 3;                          // 0..236
    int MI  = xcd * 3 + (q % 3);                 // 0..23 (== timestep t)
    int NI  = q / 3;                             // 0..78
    int i    = threadIdx.x;
    int w = i >> 6, lane = i & 63;
    int lm = lane & 15, lq = lane >> 4;
    int wr = w >> 1, wc = w & 1;

    int mm0 = ((i >> 2) & 7) ^ ((i >> 4) & 1);   // writer inverse swizzle
    int li  = i ^ mm0;
    const unsigned short* gA = Hall + (size_t)(MI * 128 + (li >> 2)) * 512 + (li & 3) * 8;
    const unsigned short* gB = Wout + (size_t)(NI * 128 + (li >> 2)) * 512 + (li & 3) * 8;
    unsigned short* lA = &ldsA[0][0] + i * 8;
    unsigned short* lB = &ldsB[0][0] + i * 8;

    auto stage = [&](int buf, int ks) {
        int go = ks * 32;
        gl16(gA + go,            lA + buf * 4096);
        gl16(gA + go + 64 * 512, lA + buf * 4096 + 2048);
        gl16(gB + go,            lB + buf * 4096);
        gl16(gB + go + 64 * 512, lB + buf * 4096 + 2048);
    };

    f32x4 acc[4][4] = {};
    stage(0, 0);
    for (int ksi = 0; ksi < 16; ksi++) {
        int cur = ksi & 1;
        if (ksi < 15) stage(cur ^ 1, ksi + 1);
        __syncthreads();                         // staging of cur complete
        bf16x8 af[4], bfr[4];
        #pragma unroll
        for (int mi = 0; mi < 4; mi++)
            af[mi] = *(const bf16x8*)&ldsA[cur][swz16(wr * 64 + mi * 16 + lm, lq)];
        #pragma unroll
        for (int ni = 0; ni < 4; ni++)
            bfr[ni] = *(const bf16x8*)&ldsB[cur][swz16(wc * 64 + ni * 16 + lm, lq)];
        #pragma unroll
        for (int mi = 0; mi < 4; mi++)
            #pragma unroll
            for (int ni = 0; ni < 4; ni++)
                acc[mi][ni] = MFMA_16x16x32_BF16(af[mi], bfr[ni], acc[mi][ni]);
        __syncthreads();                         // done reading cur
    }

    #pragma unroll
    for (int mi = 0; mi < 4; mi++) {
        #pragma unroll
        for (int r = 0; r < 4; r++) {
            int b = wr * 64 + mi * 16 + lq * 4 + r;
            float* orow = out + ((size_t)b * TP1 + MI + 1) * V_;
            #pragma unroll
            for (int ni = 0; ni < 4; ni++) {
                int n = NI * 128 + wc * 64 + ni * 16 + lm;
                if (n < V_) orow[n] = acc[mi][ni][r] + bout[n];
            }
        }
    }
}

// ---------------------------------------------------------------------------
extern "C" void kernel_launch(void* const* d_in, const int* in_sizes, int n_in,
                              void* d_out, int out_size, void* d_ws, size_t ws_size,
                              hipStream_t stream) {
    const float* images   = (const float*)d_in[0];
    const int*   captions = (const int*)d_in[1];
    const int*   cap_len  = (const int*)d_in[2];
    const float* Wemb     = (const float*)d_in[3];
    const float* Wih      = (const float*)d_in[4];
    const float* Whh      = (const float*)d_in[5];
    const float* bih      = (const float*)d_in[6];
    const float* bhh      = (const float*)d_in[7];
    const float* Wout     = (const float*)d_in[8];
    const float* bout     = (const float*)d_in[9];
    float* out = (float*)d_out;

    // workspace layout (all sizes multiples of 256B)
    char* ws = (char*)d_ws;
    unsigned short* Wih_bf  = (unsigned short*)(ws);              //  2,097,152
    unsigned short* Whh_bf  = (unsigned short*)(ws + 2097152);    //  2,097,152
    unsigned short* Wout_bf = (unsigned short*)(ws + 4194304);    // 10,354,688
    unsigned short* Xemb    = (unsigned short*)(ws + 14548992);   //  3,145,728
    unsigned short* Hall    = (unsigned short*)(ws + 17694720);   //  3,145,728
    unsigned short* h0      = (unsigned short*)(ws + 20840448);   //    131,072
    unsigned*       hx0     = (unsigned*)(ws + 20971520);         //    131,072
    unsigned*       hx1     = (unsigned*)(ws + 21102592);         //    131,072
    unsigned*       cnt     = (unsigned*)(ws + 21233664);         //      4,096
    constexpr size_t P_OFF   = 21237760;
    constexpr size_t WS_NEED = P_OFF + 25165824;   // 46,403,584
    float* P = (ws_size >= WS_NEED) ? (float*)(ws + P_OFF) : (float*)d_out;

    // staging: all fp32->bf16 in one launch (+ flag reset) + embedding
    k_cvt_all<<<7112, 256, 0, stream>>>(Wih, Whh, Wout, images,
                                        Wih_bf, Whh_bf, Wout_bf, h0, cnt);
    k_embed<<<1536, 256, 0, stream>>>(Wemb, captions, Xemb);

    // hoisted input GEMM: P = Xemb @ Wih^T + (bih + bhh)
    k_pregemm<<<384, 256, 0, stream>>>(Xemb, Wih_bf, bih, bhh, P);

    // whole recurrence in ONE persistent kernel (per-MI octet flags)
    k_lstm<<<256, 256, 0, stream>>>(P, h0, hx0, hx1, Hall, Whh_bf, cnt);

    // t=0 one-hot row + length tail
    k_start<<<1250, 256, 0, stream>>>(out, cap_len);

    // logits, LDS-staged 128x128 tiles
    k_logits<<<1896, 256, 0, stream>>>(Hall, Wout_bf, bout, out);
}

// Round 8
// 319.976 us; speedup vs baseline: 1.3395x; 1.0647x over previous
//
#include <hip/hip_runtime.h>

// ---- problem constants ----
constexpr int B_  = 128;
constexpr int T_  = 24;
constexpr int E_  = 512;
constexpr int H_  = 512;
constexpr int V_  = 10000;
constexpr int G4  = 2048;   // 4*H
constexpr int TP1 = 25;     // T+1

typedef __attribute__((ext_vector_type(8))) short bf16x8;   // 8 bf16 = 4 VGPR
typedef __attribute__((ext_vector_type(4))) short short4v;  // 4 bf16 = 8 B
typedef __attribute__((ext_vector_type(4))) float f32x4;

#define MFMA_16x16x32_BF16(a, b, c) __builtin_amdgcn_mfma_f32_16x16x32_bf16((a), (b), (c), 0, 0, 0)

// fp32 -> bf16 round-to-nearest-even (bit-level, no header ABI dependence)
__device__ inline unsigned short f2bf(float f) {
    unsigned int u = __float_as_uint(f);
    unsigned int r = (u + 0x7FFFu + ((u >> 16) & 1u)) >> 16;
    return (unsigned short)r;
}

// async global->LDS, 16B per lane. LDS dest must be linear-in-lane.
__device__ inline void gl16(const unsigned short* g, unsigned short* l) {
    __builtin_amdgcn_global_load_lds(
        (const __attribute__((address_space(1))) unsigned int*)g,
        (__attribute__((address_space(3))) unsigned int*)l, 16, 0, 0);
}

// Bank swizzle for [R][32] bf16 LDS tiles (row = 64 B = 4 granules of 16 B).
// Stored granule S = L ^ (row(L)&7). Reader:
__device__ inline int swz16(int row, int lq) {      // returns short offset
    return (((row << 2) | lq) ^ (row & 7)) << 3;
}
// Writer inverse: thread i stages stored granule i of each 256/512-granule
// chunk; logical granule li = i ^ m, m = ((i>>2)&7) ^ ((i>>4)&1).

// ---------------------------------------------------------------------------
// All fp32 -> bf16 staging in ONE launch + per-producer flag reset (256
// flags, 128B apart; graph-replay safe: first kernel on the stream).
// ---------------------------------------------------------------------------
__global__ __launch_bounds__(256) void k_cvt_all(const float* __restrict__ Wih,
                                                 const float* __restrict__ Whh,
                                                 const float* __restrict__ Wout,
                                                 const float* __restrict__ images,
                                                 unsigned short* __restrict__ dWih,
                                                 unsigned short* __restrict__ dWhh,
                                                 unsigned short* __restrict__ dWout,
                                                 unsigned short* __restrict__ dimg,
                                                 unsigned* __restrict__ flg) {
    int b = blockIdx.x;
    if (b == 0) flg[threadIdx.x * 32] = 0u;      // 256 flags
    const float* src; unsigned short* dst; int i;
    if (b < 1024)      { src = Wih;    dst = dWih;  i = b * 256 + threadIdx.x; }
    else if (b < 2048) { src = Whh;    dst = dWhh;  i = (b - 1024) * 256 + threadIdx.x; }
    else if (b < 7048) { src = Wout;   dst = dWout; i = (b - 2048) * 256 + threadIdx.x; }
    else               { src = images; dst = dimg;  i = (b - 7048) * 256 + threadIdx.x; }
    float4 v = ((const float4*)src)[i];
    short4v o;
    o[0] = (short)f2bf(v.x); o[1] = (short)f2bf(v.y);
    o[2] = (short)f2bf(v.z); o[3] = (short)f2bf(v.w);
    ((short4v*)dst)[i] = o;
}

// ---------------------------------------------------------------------------
// Embedding gather -> bf16, padding_idx(0) -> zeros.
// ---------------------------------------------------------------------------
__global__ __launch_bounds__(256) void k_embed(const float* __restrict__ Wemb,
                                               const int* __restrict__ captions,
                                               unsigned short* __restrict__ Xemb) {
    int i = blockIdx.x * 256 + threadIdx.x;     // one thread per 4 elems
    if (i >= 3072 * 128) return;
    int row = i >> 7;                           // m = t*128 + b
    int k4  = i & 127;
    int b = row & 127, t = row >> 7;
    int tok = captions[b * T_ + t];
    short4v o = {0, 0, 0, 0};
    if (tok > 0 && tok < V_) {                  // tok==0 is padding -> zeros
        float4 v = ((const float4*)(Wemb + (long)tok * E_))[k4];
        o[0] = (short)f2bf(v.x); o[1] = (short)f2bf(v.y);
        o[2] = (short)f2bf(v.z); o[3] = (short)f2bf(v.w);
    }
    ((short4v*)Xemb)[(long)row * 128 + k4] = o;
}

// ---------------------------------------------------------------------------
// t=0 one-hot row (only) + (captions_length - 1) tail.
// ---------------------------------------------------------------------------
__global__ __launch_bounds__(256) void k_start(float* __restrict__ out,
                                               const int* __restrict__ cap_len) {
    int idx = blockIdx.x * 256 + threadIdx.x;
    constexpr int Q = V_ / 4;                    // 2500 float4 per row
    if (idx < B_ * Q) {
        int b = idx / Q;
        int q = idx - b * Q;
        float4 zero = {0.f, 0.f, 0.f, 0.f};
        float4 one1 = {0.f, 1.f, 0.f, 0.f};      // one-hot at v=1
        ((float4*)out)[(long)b * (TP1 * Q) + q] = (q == 0) ? one1 : zero;
    }
    if (idx < B_) {
        out[(size_t)B_ * TP1 * V_ + idx] = (float)(cap_len[idx] - 1);
    }
}

// ---------------------------------------------------------------------------
// P[m][n] = Xemb[m].Wih[n] + bih[n] + bhh[n]  (fp32). M=3072, N=2048, K=512.
// 128x128 LDS-staged tiles, XCD-swizzled. (Unchanged — passing.)
// ---------------------------------------------------------------------------
__global__ __launch_bounds__(256) void k_pregemm(const unsigned short* __restrict__ Xemb,
                                                 const unsigned short* __restrict__ Wih,
                                                 const float* __restrict__ bih,
                                                 const float* __restrict__ bhh,
                                                 float* __restrict__ P) {
    __shared__ unsigned short ldsA[2][4096];     // [buf][128*32] swizzled
    __shared__ unsigned short ldsB[2][4096];
    int bid = blockIdx.x;
    int xcd = bid & 7;
    int q   = bid >> 3;                          // 0..47
    int MI  = xcd * 3 + (q % 3);                 // 0..23
    int NI  = q / 3;                             // 0..15
    int i    = threadIdx.x;
    int w = i >> 6, lane = i & 63;
    int lm = lane & 15, lq = lane >> 4;
    int wr = w >> 1, wc = w & 1;

    int mm0 = ((i >> 2) & 7) ^ ((i >> 4) & 1);   // writer inverse swizzle
    int li  = i ^ mm0;
    const unsigned short* gA = Xemb + (size_t)(MI * 128 + (li >> 2)) * 512 + (li & 3) * 8;
    const unsigned short* gB = Wih  + (size_t)(NI * 128 + (li >> 2)) * 512 + (li & 3) * 8;
    unsigned short* lA = &ldsA[0][0] + i * 8;
    unsigned short* lB = &ldsB[0][0] + i * 8;

    auto stage = [&](int buf, int ks) {
        int go = ks * 32;
        gl16(gA + go,            lA + buf * 4096);
        gl16(gA + go + 64 * 512, lA + buf * 4096 + 2048);
        gl16(gB + go,            lB + buf * 4096);
        gl16(gB + go + 64 * 512, lB + buf * 4096 + 2048);
    };

    f32x4 acc[4][4] = {};
    stage(0, 0);
    for (int ksi = 0; ksi < 16; ksi++) {
        int cur = ksi & 1;
        if (ksi < 15) stage(cur ^ 1, ksi + 1);
        __syncthreads();
        bf16x8 af[4], bfr[4];
        #pragma unroll
        for (int mi = 0; mi < 4; mi++)
            af[mi] = *(const bf16x8*)&ldsA[cur][swz16(wr * 64 + mi * 16 + lm, lq)];
        #pragma unroll
        for (int ni = 0; ni < 4; ni++)
            bfr[ni] = *(const bf16x8*)&ldsB[cur][swz16(wc * 64 + ni * 16 + lm, lq)];
        #pragma unroll
        for (int mi = 0; mi < 4; mi++)
            #pragma unroll
            for (int ni = 0; ni < 4; ni++)
                acc[mi][ni] = MFMA_16x16x32_BF16(af[mi], bfr[ni], acc[mi][ni]);
        __syncthreads();
    }

    float bias[4];
    #pragma unroll
    for (int ni = 0; ni < 4; ni++) {
        int n = NI * 128 + wc * 64 + ni * 16 + lm;
        bias[ni] = bih[n] + bhh[n];
    }
    #pragma unroll
    for (int mi = 0; mi < 4; mi++) {
        #pragma unroll
        for (int r = 0; r < 4; r++) {
            int m = MI * 128 + wr * 64 + mi * 16 + lq * 4 + r;
            #pragma unroll
            for (int ni = 0; ni < 4; ni++) {
                int n = NI * 128 + wc * 64 + ni * 16 + lm;
                P[(size_t)m * G4 + n] = acc[mi][ni][r] + bias[ni];
            }
        }
    }
}

// ---------------------------------------------------------------------------
// Persistent LSTM recurrence with PER-PRODUCER flags (no RMW contention).
// Block (MI,HG) plain-stores flag[MI*32+HG] = t+1 after its h[t] stores
// drain. Consumer wave w's lanes 0..7 poll octet w's 8 flags in parallel.
// WAR-safe by the same induction as R7: a block's 4 waves collectively wait
// on all 32 same-MI flags >= t before any h-store of step t, so every read
// of the slot being overwritten has completed. h exchange via agent-scope
// relaxed atomics (coherence-point ops, no threadfence -> per-XCD L2 with
// Whh/P stays warm).
// ---------------------------------------------------------------------------
__global__ __launch_bounds__(256, 1) void k_lstm(const float* __restrict__ P,
                                                 const unsigned short* __restrict__ h0,
                                                 unsigned* __restrict__ hx0,
                                                 unsigned* __restrict__ hx1,
                                                 unsigned short* __restrict__ Hall,
                                                 const unsigned short* __restrict__ Whh,
                                                 unsigned* __restrict__ flg) {
    __shared__ float part[16][4][64];            // [g*4+r][wave][lane]
    int w    = threadIdx.x >> 6;                 // 0..3 (K-slice / cell row)
    int lane = threadIdx.x & 63;
    int lm = lane & 15, lq = lane >> 4;
    int MI = blockIdx.x >> 5;                    // 0..7
    int HG = blockIdx.x & 31;                    // 0..31
    int hcol = HG * 16 + lm;
    int ks = w * 128;
    int brow = MI * 16 + lq * 4 + w;             // this lane's cell row (b)
    unsigned* myFlg = flg + (MI * 32 + HG) * 32;          // producer flag
    unsigned* wFlg  = flg + (MI * 32 + (w << 3)) * 32;    // octet-w flag base

    // resident Whh fragments (bf16), reused all 24 steps
    bf16x8 bw[4][4];                             // [gate][kk]
    #pragma unroll
    for (int g = 0; g < 4; g++)
        #pragma unroll
        for (int kk = 0; kk < 4; kk++)
            bw[g][kk] = *(const bf16x8*)((const short*)Whh +
                          (size_t)(g * 512 + hcol) * 512 + ks + kk * 32 + lq * 8);

    float cp = 0.f;                              // c[brow][hcol] in-register

    for (int t = 0; t < T_; t++) {
        // ---- P (xW + bias): issue before the poll so it flies during it ----
        const float* Pr = P + (size_t)t * B_ * G4 + (size_t)brow * G4;
        float pv0 = Pr[0 * 512 + hcol];
        float pv1 = Pr[1 * 512 + hcol];
        float pv2 = Pr[2 * 512 + hcol];
        float pv3 = Pr[3 * 512 + hcol];

        // ---- A fragments (h rows MI*16+lm, this wave's K-slice) ----
        bf16x8 a[4];
        if (t == 0) {
            const unsigned short* A = h0 + (size_t)(MI * 16 + lm) * 512 + ks;
            #pragma unroll
            for (int kk = 0; kk < 4; kk++)
                a[kk] = *(const bf16x8*)(A + kk * 32 + lq * 8);
        } else {
            // parallel poll: lanes 0..7 watch octet w's 8 producer flags
            if (lane < 8) {
                unsigned want = (unsigned)t;
                while (__hip_atomic_load(wFlg + lane * 32, __ATOMIC_RELAXED,
                                         __HIP_MEMORY_SCOPE_AGENT) < want)
                    __builtin_amdgcn_s_sleep(1);
            }
            __builtin_amdgcn_wave_barrier();
            asm volatile("" ::: "memory");
            const unsigned long long* A = (const unsigned long long*)
                (((t & 1) ? hx1 : hx0) + ((size_t)(MI * 16 + lm) * 512 + ks) / 2);
            #pragma unroll
            for (int kk = 0; kk < 4; kk++) {
                union { unsigned long long q[2]; bf16x8 v; } cv;
                cv.q[0] = __hip_atomic_load(A + kk * 8 + lq * 2,
                                            __ATOMIC_RELAXED, __HIP_MEMORY_SCOPE_AGENT);
                cv.q[1] = __hip_atomic_load(A + kk * 8 + lq * 2 + 1,
                                            __ATOMIC_RELAXED, __HIP_MEMORY_SCOPE_AGENT);
                a[kk] = cv.v;
            }
        }

        // ---- GEMM slice ----
        f32x4 acc[4] = {};
        #pragma unroll
        for (int kk = 0; kk < 4; kk++) {
            acc[0] = MFMA_16x16x32_BF16(a[kk], bw[0][kk], acc[0]);
            acc[1] = MFMA_16x16x32_BF16(a[kk], bw[1][kk], acc[1]);
            acc[2] = MFMA_16x16x32_BF16(a[kk], bw[2][kk], acc[2]);
            acc[3] = MFMA_16x16x32_BF16(a[kk], bw[3][kk], acc[3]);
        }

        #pragma unroll
        for (int g = 0; g < 4; g++)
            #pragma unroll
            for (int r = 0; r < 4; r++)
                part[g * 4 + r][w][lane] = acc[g][r];
        __syncthreads();

        // ---- reduce + cell (wave w handles row r==w) ----
        float gi = part[0*4+w][0][lane] + part[0*4+w][1][lane] + part[0*4+w][2][lane] + part[0*4+w][3][lane] + pv0;
        float gf = part[1*4+w][0][lane] + part[1*4+w][1][lane] + part[1*4+w][2][lane] + part[1*4+w][3][lane] + pv1;
        float gg = part[2*4+w][0][lane] + part[2*4+w][1][lane] + part[2*4+w][2][lane] + part[2*4+w][3][lane] + pv2;
        float go = part[3*4+w][0][lane] + part[3*4+w][1][lane] + part[3*4+w][2][lane] + part[3*4+w][3][lane] + pv3;
        float si = 1.f / (1.f + expf(-gi));
        float sf = 1.f / (1.f + expf(-gf));
        float so = 1.f / (1.f + expf(-go));
        float cn = sf * cp + si * tanhf(gg);
        float hn = so * tanhf(cn);
        cp = cn;
        unsigned short hb = f2bf(hn);
        Hall[(size_t)t * (B_ * H_) + brow * 512 + hcol] = hb;   // normal store

        if (t < T_ - 1) {
            // pair adjacent hcols into one uint, agent-scope store (coherent)
            unsigned up = ((unsigned)(unsigned short)__shfl_down((int)hb, 1) << 16) | (unsigned)hb;
            unsigned* HW = (t & 1) ? hx0 : hx1;  // step t writes; t+1 reads
            if (!(lm & 1))
                __hip_atomic_store(HW + (brow * 512 + hcol) / 2, up,
                                   __ATOMIC_RELAXED, __HIP_MEMORY_SCOPE_AGENT);
            // each wave drains ITS OWN h stores before the block signals
            asm volatile("s_waitcnt vmcnt(0)" ::: "memory");
            __syncthreads();
            if (threadIdx.x == 0)
                __hip_atomic_store(myFlg, (unsigned)(t + 1), __ATOMIC_RELAXED,
                                   __HIP_MEMORY_SCOPE_AGENT);
        }
    }
}

// ---------------------------------------------------------------------------
// Logits: Hall[3072,512](bf16) @ Wout_bf^T + b_out -> fp32 out[b][t+1][v].
// 128x256 tile, 512 thr / 8 waves (wave = 64x64, acc 4x4, ~120 VGPR), BK=32,
// double-buffered global_load_lds, swizzled LDS. Grid 8*(3*40) = 960 blocks;
// XCD owns 3 M-tiles, streams 40 B-panels. Wout padded to 10240 rows.
// ---------------------------------------------------------------------------
__global__ __launch_bounds__(512) void k_logits(const unsigned short* __restrict__ Hall,
                                                const unsigned short* __restrict__ Wout,
                                                const float* __restrict__ bout,
                                                float* __restrict__ out) {
    __shared__ unsigned short ldsA[2][4096];     // [buf][128*32] swizzled
    __shared__ unsigned short ldsB[2][8192];     // [buf][256*32] swizzled
    int bid = blockIdx.x;
    int xcd = bid & 7;
    int q   = bid >> 3;                          // 0..119
    int MI  = xcd * 3 + (q % 3);                 // 0..23 (== timestep t)
    int NI  = q / 3;                             // 0..39
    int i    = threadIdx.x;                      // 0..511
    int w = i >> 6, lane = i & 63;
    int lm = lane & 15, lq = lane >> 4;
    int wr = w >> 2, wc = w & 3;                 // 2 x 4 wave grid

    int mm0 = ((i >> 2) & 7) ^ ((i >> 4) & 1);   // writer inverse swizzle
    int li  = i ^ mm0;
    const unsigned short* gA = Hall + (size_t)(MI * 128 + (li >> 2)) * 512 + (li & 3) * 8;
    const unsigned short* gB = Wout + (size_t)(NI * 256 + (li >> 2)) * 512 + (li & 3) * 8;
    unsigned short* lA = &ldsA[0][0] + i * 8;
    unsigned short* lB = &ldsB[0][0] + i * 8;

    auto stage = [&](int buf, int ks) {
        int go = ks * 32;
        gl16(gA + go,             lA + buf * 4096);
        gl16(gB + go,             lB + buf * 8192);
        gl16(gB + go + 128 * 512, lB + buf * 8192 + 4096);
    };

    f32x4 acc[4][4] = {};
    stage(0, 0);
    for (int ksi = 0; ksi < 16; ksi++) {
        int cur = ksi & 1;
        if (ksi < 15) stage(cur ^ 1, ksi + 1);
        __syncthreads();                         // staging of cur complete
        bf16x8 af[4], bfr[4];
        #pragma unroll
        for (int mi = 0; mi < 4; mi++)
            af[mi] = *(const bf16x8*)&ldsA[cur][swz16(wr * 64 + mi * 16 + lm, lq)];
        #pragma unroll
        for (int ni = 0; ni < 4; ni++)
            bfr[ni] = *(const bf16x8*)&ldsB[cur][swz16(wc * 64 + ni * 16 + lm, lq)];
        #pragma unroll
        for (int mi = 0; mi < 4; mi++)
            #pragma unroll
            for (int ni = 0; ni < 4; ni++)
                acc[mi][ni] = MFMA_16x16x32_BF16(af[mi], bfr[ni], acc[mi][ni]);
        __syncthreads();                         // done reading cur
    }

    // epilogue: rows of this M-tile are exactly (t = MI, b = 0..127)
    #pragma unroll
    for (int mi = 0; mi < 4; mi++) {
        #pragma unroll
        for (int r = 0; r < 4; r++) {
            int b = wr * 64 + mi * 16 + lq * 4 + r;
            float* orow = out + ((size_t)b * TP1 + MI + 1) * V_;
            #pragma unroll
            for (int ni = 0; ni < 4; ni++) {
                int n = NI * 256 + wc * 64 + ni * 16 + lm;
                if (n < V_) orow[n] = acc[mi][ni][r] + bout[n];
            }
        }
    }
}

// ---------------------------------------------------------------------------
extern "C" void kernel_launch(void* const* d_in, const int* in_sizes, int n_in,
                              void* d_out, int out_size, void* d_ws, size_t ws_size,
                              hipStream_t stream) {
    const float* images   = (const float*)d_in[0];
    const int*   captions = (const int*)d_in[1];
    const int*   cap_len  = (const int*)d_in[2];
    const float* Wemb     = (const float*)d_in[3];
    const float* Wih      = (const float*)d_in[4];
    const float* Whh      = (const float*)d_in[5];
    const float* bih      = (const float*)d_in[6];
    const float* bhh      = (const float*)d_in[7];
    const float* Wout     = (const float*)d_in[8];
    const float* bout     = (const float*)d_in[9];
    float* out = (float*)d_out;

    // workspace layout (all sizes multiples of 256B)
    char* ws = (char*)d_ws;
    unsigned short* Wih_bf  = (unsigned short*)(ws);              //  2,097,152
    unsigned short* Whh_bf  = (unsigned short*)(ws + 2097152);    //  2,097,152
    unsigned short* Wout_bf = (unsigned short*)(ws + 4194304);    // 10,485,760 (10240 rows)
    unsigned short* Xemb    = (unsigned short*)(ws + 14680064);   //  3,145,728
    unsigned short* Hall    = (unsigned short*)(ws + 17825792);   //  3,145,728
    unsigned short* h0      = (unsigned short*)(ws + 20971520);   //    131,072
    unsigned*       hx0     = (unsigned*)(ws + 21102592);         //    131,072
    unsigned*       hx1     = (unsigned*)(ws + 21233664);         //    131,072
    unsigned*       flg     = (unsigned*)(ws + 21364736);         //     32,768
    constexpr size_t P_OFF   = 21397504;
    constexpr size_t WS_NEED = P_OFF + 25165824;   // 46,563,328
    bool ws_ok = (ws_size >= WS_NEED);
    float* P = ws_ok ? (float*)(ws + P_OFF) : (float*)d_out;

    // staging: all fp32->bf16 in one launch (+ flag reset) + embedding
    k_cvt_all<<<7112, 256, 0, stream>>>(Wih, Whh, Wout, images,
                                        Wih_bf, Whh_bf, Wout_bf, h0, flg);
    k_embed<<<1536, 256, 0, stream>>>(Wemb, captions, Xemb);

    // hoisted input GEMM: P = Xemb @ Wih^T + (bih + bhh)
    k_pregemm<<<384, 256, 0, stream>>>(Xemb, Wih_bf, bih, bhh, P);

    // t=0 one-hot row + tail: early when P is in workspace (no out aliasing)
    if (ws_ok) k_start<<<1250, 256, 0, stream>>>(out, cap_len);

    // whole recurrence in ONE persistent kernel (per-producer flags)
    k_lstm<<<256, 256, 0, stream>>>(P, h0, hx0, hx1, Hall, Whh_bf, flg);

    if (!ws_ok) k_start<<<1250, 256, 0, stream>>>(out, cap_len);

    // logits: 128x256 tiles, 512 threads
    k_logits<<<960, 512, 0, stream>>>(Hall, Wout_bf, bout, out);
}